// Round 7
// baseline (117.866 us; speedup 1.0000x reference)
//
#include <hip/hip_runtime.h>
#include <hip/hip_bf16.h>

typedef __bf16 bf16x8 __attribute__((ext_vector_type(8)));
typedef float  f32x4  __attribute__((ext_vector_type(4)));

#define NB 16
#define CI 128
#define CO 128
#define HH 64
#define WW 64
#define QSZ ((size_t)NB * HH * WW * 32)      // elems per ch-quarter of xT

// prep: blk<1024: transpose+cvt x -> xT (ch-innermost, 4 quarters) + per-pixel
// parity sums S (fp32). 1024..1095: w -> A-frag order. 1096..1223: wsum.
__global__ void prep(const float* __restrict__ x, const float* __restrict__ w,
                     __bf16* __restrict__ Ag, float* __restrict__ wsum,
                     __bf16* __restrict__ xT, float* __restrict__ S) {
    __shared__ float tile[128 * 65];          // 33280 B
    __shared__ float red[8];
    const int blk = blockIdx.x, tid = threadIdx.x;
    if (blk < 1024) {
        const int bb = blk >> 6, y = blk & 63;
        const float* xr = x + ((size_t)bb * CI) * (HH * WW) + y * WW;
        for (int idx = tid; idx < 2048; idx += 256) {   // 128 c x 16 float4
            int c = idx >> 4, x4 = idx & 15;
            float4 v = *(const float4*)(xr + (size_t)c * (HH * WW) + x4 * 4);
            *(float4*)(tile + c * 65 + x4 * 4) = v;
        }
        __syncthreads();
        // store mapping: cg4 = tid&3, px = tid>>2 -> wave writes 1KB contiguous
        const int cg4 = tid & 3, px = (tid >> 2) & 63;
        #pragma unroll
        for (int k = 0; k < 4; ++k) {         // quarter
            bf16x8 o8;
            #pragma unroll
            for (int j = 0; j < 8; ++j)
                o8[j] = (__bf16)tile[((k * 4 + cg4) * 8 + j) * 65 + px];
            *(bf16x8*)(xT + (size_t)k * QSZ
                       + (((size_t)bb * 64 + y) * 64 + px) * 32 + cg4 * 8) = o8;
        }
        if (tid < 64) {                                 // fp32 parity sums
            float se = 0.f, so = 0.f;
            #pragma unroll 8
            for (int c = 0; c < 128; c += 2) {
                se += tile[c * 65 + tid];
                so += tile[(c + 1) * 65 + tid];
            }
            float2 v = {se, so};
            *(float2*)(S + (((size_t)bb * 64 + y) * 64 + tid) * 2) = v;
        }
    } else if (blk < 1096) {
        int gid  = (blk - 1024) * 256 + tid;            // [0, 18432)
        int l    = gid & 63;
        int frag = gid >> 6;                            // t*8 + mt
        int mt   = frag & 7;
        int t    = frag >> 3;                           // [0, 36)
        int tap  = t >> 2;
        int r    = tap % 3;
        int s    = tap / 3;
        int o    = mt * 16 + (l & 15);
        int cb   = (t & 3) * 32 + (l >> 4) * 8;
        bf16x8 v;
        #pragma unroll
        for (int j = 0; j < 8; ++j)
            v[j] = (__bf16)w[((o * CI + cb + j) * 3 + r) * 3 + s];
        *(bf16x8*)(Ag + (size_t)gid * 8) = v;
    } else {
        int o = blk - 1096;
        const float* p = w + (size_t)o * CI * 9;
        float se = 0.f, so = 0.f;
        for (int idx = tid; idx < CI * 9; idx += 256) {
            int c = idx / 9;
            float v = p[idx];
            if (c & 1) so += v; else se += v;
        }
        #pragma unroll
        for (int off = 32; off; off >>= 1) {
            se += __shfl_down(se, off);
            so += __shfl_down(so, off);
        }
        int wv = tid >> 6, lane = tid & 63;
        if (lane == 0) { red[wv * 2] = se; red[wv * 2 + 1] = so; }
        __syncthreads();
        if (tid == 0) {
            wsum[o]      = red[0] + red[2] + red[4] + red[6];
            wsum[CO + o] = red[1] + red[3] + red[5] + red[7];
        }
    }
}

// One block = (batch, 4-row group): M=128 x N=256 x K=1152. 256 blocks = 1/CU.
// A: single 72KB LDS buffer, double-buffered THROUGH REGISTERS (glb->VGPR at
// quarter start, ds_write at quarter end between 2 barriers). B: straight from
// xT global into a depth-3 rotating register pipeline (per-lane clamped addrs).
// Inner 9-tap loop: ds_read(A) + MFMA only — no barriers, no GLDS, no aliasing.
__global__ __launch_bounds__(512, 2) void conv_main(
        const __bf16* __restrict__ xT,
        const float* __restrict__ S,
        const float* __restrict__ bias,
        const float* __restrict__ wsum,
        const __bf16* __restrict__ Ag,
        float* __restrict__ out)
{
    __shared__ __align__(16) __bf16 Alds[9 * 4096];        // 73728 B
    __shared__ float SrowS[6 * 64 * 2];                    //  3072 B
    __shared__ float avgl[512];                            //  2048 B

    const int tid  = threadIdx.x;
    const int b    = blockIdx.y;
    const int row0 = blockIdx.x * 4;          // output rows row0..row0+3

    const int wave = tid >> 6, lane = tid & 63;
    const int wm = wave >> 2;                 // o-half
    const int wn = wave & 3;                  // output row within group
    const int m = lane & 15, qv = lane >> 4;

    // ---- A(q=0): global -> regs (chunk tap=k, part=wave) ----
    bf16x8 Areg[9];
    #pragma unroll
    for (int k = 0; k < 9; ++k)
        Areg[k] = *(const bf16x8*)(Ag + (((size_t)((k * 4 + 0) * 8 + wave)) << 9)
                                      + (lane << 3));

    // ---- gather S halo rows ----
    for (int idx = tid; idx < 768; idx += 512) {    // 6 rows x 64 cols x 2 par
        int r = idx >> 7, rem = idx & 127;
        int col = rem >> 1, uu = idx & 1;
        int yi = row0 - 1 + r; yi = yi < 0 ? 0 : (yi > 63 ? 63 : yi);
        SrowS[idx] = S[(((size_t)b * 64 + yi) * 64 + col) * 2 + uu];
    }
    __syncthreads();
    {   // 3x3 clamped box mean per (out-row, col, parity)
        int rr = tid >> 7, col = (tid >> 1) & 63, uu = tid & 1;
        float ssum = 0.f;
        #pragma unroll
        for (int dy = 0; dy < 3; ++dy)
            #pragma unroll
            for (int dx = 0; dx < 3; ++dx) {
                int cc = col - 1 + dx; cc = cc < 0 ? 0 : (cc > 63 ? 63 : cc);
                ssum += SrowS[((rr + dy) * 64 + cc) * 2 + uu];
            }
        avgl[tid] = ssum * (1.0f / 576.0f);
    }
    // ---- ds_write A(0) ----
    #pragma unroll
    for (int k = 0; k < 9; ++k)
        *(bf16x8*)(Alds + (((size_t)(k * 8 + wave)) << 9) + (lane << 3)) = Areg[k];

    // ---- per-lane B addressing (clamped halo) ----
    int boffs[4][3];
    #pragma unroll
    for (int nt = 0; nt < 4; ++nt)
        #pragma unroll
        for (int r3 = 0; r3 < 3; ++r3) {
            int xi = nt * 16 + m - 1 + r3;
            xi = xi < 0 ? 0 : (xi > 63 ? 63 : xi);
            boffs[nt][r3] = xi * 32 + qv * 8;
        }
    size_t rowbase[3];
    #pragma unroll
    for (int s_ = 0; s_ < 3; ++s_) {
        int yi = row0 + wn - 1 + s_; yi = yi < 0 ? 0 : (yi > 63 ? 63 : yi);
        rowbase[s_] = ((size_t)b * 64 + yi) << 11;       // *64*32 elems
    }

    f32x4 acc[4][4];
    #pragma unroll
    for (int i = 0; i < 4; ++i)
        #pragma unroll
        for (int j = 0; j < 4; ++j)
            acc[i][j] = (f32x4){0.f, 0.f, 0.f, 0.f};

    // ---- B prologue: steps 0..2 into depth-3 pipeline ----
    bf16x8 Bv[4][4];
    #pragma unroll
    for (int st = 0; st < 3; ++st) {
        const int s_ = st / 3, r3 = st % 3;              // q=0, tap=st
        #pragma unroll
        for (int nt = 0; nt < 4; ++nt)
            Bv[st & 3][nt] = *(const bf16x8*)(xT + rowbase[s_] + boffs[nt][r3]);
    }
    __syncthreads();                          // A(0) in LDS visible

    #pragma unroll
    for (int q = 0; q < 4; ++q) {
        if (q < 3) {                          // A(q+1): global -> regs, in flight
            #pragma unroll
            for (int k = 0; k < 9; ++k)
                Areg[k] = *(const bf16x8*)(Ag
                    + (((size_t)((k * 4 + q + 1) * 8 + wave)) << 9) + (lane << 3));
        }
        #pragma unroll
        for (int tap = 0; tap < 9; ++tap) {
            const int st = q * 9 + tap;
            if (st + 3 < 36) {                // issue B(st+3)
                const int s2 = st + 3, q2 = s2 / 9, t2 = s2 % 9;
                const int ss = t2 / 3, rr3 = t2 % 3;
                #pragma unroll
                for (int nt = 0; nt < 4; ++nt)
                    Bv[s2 & 3][nt] = *(const bf16x8*)(xT + (size_t)q2 * QSZ
                        + rowbase[ss] + boffs[nt][rr3]);
            }
            bf16x8 Af[4];
            #pragma unroll
            for (int i = 0; i < 4; ++i)
                Af[i] = *(const bf16x8*)(Alds
                    + (((size_t)(tap * 8 + wm * 4 + i)) << 9) + (lane << 3));
            #pragma unroll
            for (int i = 0; i < 4; ++i)
                #pragma unroll
                for (int nt = 0; nt < 4; ++nt)
                    acc[i][nt] = __builtin_amdgcn_mfma_f32_16x16x32_bf16(
                        Af[i], Bv[st & 3][nt], acc[i][nt], 0, 0, 0);
        }
        if (q < 3) {
            __syncthreads();                  // all waves done reading A(q)
            #pragma unroll
            for (int k = 0; k < 9; ++k)
                *(bf16x8*)(Alds + (((size_t)(k * 8 + wave)) << 9)
                           + (lane << 3)) = Areg[k];
            __syncthreads();                  // A(q+1) visible
        }
    }

    // ---- epilogue ----
    float a0v[4], a1v[4];
    #pragma unroll
    for (int nt = 0; nt < 4; ++nt) {
        int col = nt * 16 + m;
        a0v[nt] = avgl[wn * 128 + col * 2 + 0];
        a1v[nt] = avgl[wn * 128 + col * 2 + 1];
    }
    float* outb = out + (size_t)b * CO * HH * WW + (size_t)(row0 + wn) * WW;
    #pragma unroll
    for (int i = 0; i < 4; ++i) {
        #pragma unroll
        for (int rg = 0; rg < 4; ++rg) {
            int o = wm * 64 + i * 16 + qv * 4 + rg;  // C/D row = (lane>>4)*4+reg
            float bo = bias[o];
            float w0 = wsum[o];
            float w1 = wsum[CO + o];
            float* po = outb + (size_t)o * (HH * WW);
            #pragma unroll
            for (int nt = 0; nt < 4; ++nt) {
                float v = acc[i][nt][rg] + bo - a0v[nt] * w0 - a1v[nt] * w1;
                v = v > 0.f ? v : 0.01f * v;
                v += (o & 1) ? a1v[nt] : a0v[nt];
                __builtin_nontemporal_store(v, po + nt * 16 + m);
            }
        }
    }
}

extern "C" void kernel_launch(void* const* d_in, const int* in_sizes, int n_in,
                              void* d_out, int out_size, void* d_ws, size_t ws_size,
                              hipStream_t stream) {
    const float* x    = (const float*)d_in[0];
    const float* w    = (const float*)d_in[1];
    const float* bias = (const float*)d_in[2];
    float* out = (float*)d_out;

    __bf16* Ag   = (__bf16*)d_ws;                     // 294912 B, frag-order w
    float*  wsum = (float*)((char*)d_ws + 294912);    // 1024 B
    __bf16* xT   = (__bf16*)((char*)d_ws + 295936);   // 16 MB, 4 ch-quarters
    float*  S    = (float*)((char*)d_ws + 295936 + 2 * QSZ * 4);  // 512 KB

    prep<<<1224, 256, 0, stream>>>(x, w, Ag, wsum, xT, S);

    dim3 grid(HH / 4, NB);                            // 16 row-groups x 16 b
    conv_main<<<grid, 512, 0, stream>>>(xT, S, bias, wsum, Ag, out);
}